// Round 1
// baseline (3493.343 us; speedup 1.0000x reference)
//
#include <hip/hip_runtime.h>

// Residual VQ: B=16, D=128, L=4096, K=8 codebooks x N=1024 entries.
// out0 (B,K,D,L) cumulative quantization sums, out1 (B,L,K) argmin indices
// (written as float; harness reads whole buffer as float32).
//
// Structure: 1 cnorm kernel + 8 sequential rvq_step kernels (stream-ordered).
// Residual for step k is recomputed as x - out0[b][k-1] (the cumulative plane
// written by the previous step) -- no residual workspace needed.

#define BB 16
#define DD 128
#define LL 4096
#define KK 8
#define NN 1024

constexpr int TL = 64;            // l-positions per block
constexpr int TN = 64;            // n per chunk (full argmin kept in-block)
constexpr int NCHUNK = NN / TN;   // 16
constexpr int XSTR = DD + 4;      // 132 floats: pad keeps b128 16B-aligned, breaks bank stride
constexpr int CSTR = 64 + 4;      // 68 floats (half-D staging rows)

__global__ void cnorm_kernel(const float* __restrict__ cb, float* __restrict__ cnorm) {
    int row = blockIdx.x * blockDim.x + threadIdx.x;   // 0..K*N-1
    const float4* p = (const float4*)(cb + (size_t)row * DD);
    float s = 0.f;
#pragma unroll
    for (int i = 0; i < DD / 4; ++i) {
        float4 v = p[i];
        s += v.x * v.x + v.y * v.y + v.z * v.z + v.w * v.w;
    }
    cnorm[row] = s;
}

__global__ __launch_bounds__(256, 2) void rvq_step(
    const float* __restrict__ x,
    const float* __restrict__ cbk,     // codebook k base (N*D)
    const float* __restrict__ cnormk,  // N
    float* __restrict__ out0,          // B*K*D*L
    float* __restrict__ out1,          // B*L*K (float-encoded indices)
    int k)
{
    __shared__ float xs[TL * XSTR];       // residual tile, [l][d], 33792 B
    __shared__ float cs[TN * CSTR];       // cb half-chunk, [n][d_half], 17408 B
    __shared__ float red_v[TL * 17];      // argmin reduce vals
    __shared__ int   red_n[TL * 17];      // argmin reduce idx
    __shared__ int   idx_final[TL];

    const int tid = threadIdx.x;
    const int bidx = blockIdx.x;
    const int b  = bidx / (LL / TL);
    const int l0 = (bidx % (LL / TL)) * TL;

    const float* prev = (k > 0) ? (out0 + ((size_t)b * KK + (k - 1)) * DD * LL) : nullptr;
    float* cur = out0 + ((size_t)b * KK + k) * DD * LL;

    // ---- Phase 1: residual tile -> LDS (coalesced along l) ----
    {
        const int ll = tid & 63;
        const int d0 = tid >> 6;  // 0..3
#pragma unroll
        for (int i = 0; i < DD / 4; ++i) {
            int d = d0 + i * 4;
            size_t gi = ((size_t)b * DD + d) * LL + l0 + ll;
            float v = x[gi];
            if (k > 0) v -= prev[(size_t)d * LL + l0 + ll];
            xs[ll * XSTR + d] = v;
        }
    }
    __syncthreads();

    const int ti = tid >> 4;   // 0..15, owns l = l0 + ti*4 + r
    const int tj = tid & 15;   // 0..15, owns n = n0 + tj*4 + s

    float minv[4];
    int   minn[4];
#pragma unroll
    for (int r = 0; r < 4; ++r) { minv[r] = 3.4e38f; minn[r] = 0; }

    // ---- Phase 2: fused score GEMM + running per-thread argmin ----
    for (int c = 0; c < NCHUNK; ++c) {
        const int n0 = c * TN;
        float acc[4][4];
#pragma unroll
        for (int r = 0; r < 4; ++r)
#pragma unroll
            for (int s = 0; s < 4; ++s) acc[r][s] = 0.f;

#pragma unroll
        for (int h = 0; h < 2; ++h) {
            // stage 64n x 64d half-chunk of cb into LDS
            {
                const int row = tid >> 2;   // 0..63
                const int q   = tid & 3;    // 0..3
                const float4* src = (const float4*)(cbk + (size_t)(n0 + row) * DD + h * 64 + q * 16);
                float4* dst = (float4*)(cs + row * CSTR + q * 16);
#pragma unroll
                for (int j = 0; j < 4; ++j) dst[j] = src[j];
            }
            __syncthreads();
#pragma unroll
            for (int dq = 0; dq < 16; ++dq) {
                float4 xa[4], cv[4];
#pragma unroll
                for (int r = 0; r < 4; ++r)
                    xa[r] = *(const float4*)(xs + (ti * 4 + r) * XSTR + h * 64 + dq * 4);
#pragma unroll
                for (int s = 0; s < 4; ++s)
                    cv[s] = *(const float4*)(cs + (tj * 4 + s) * CSTR + dq * 4);
#pragma unroll
                for (int r = 0; r < 4; ++r)
#pragma unroll
                    for (int s = 0; s < 4; ++s)
                        acc[r][s] += xa[r].x * cv[s].x + xa[r].y * cv[s].y
                                   + xa[r].z * cv[s].z + xa[r].w * cv[s].w;
            }
            __syncthreads();
        }

        // score = ||c||^2 - 2*dot  (x-norm constant per l, dropped: argmin-invariant)
        float4 cn = *(const float4*)(cnormk + n0 + tj * 4);
        float cna[4] = {cn.x, cn.y, cn.z, cn.w};
#pragma unroll
        for (int r = 0; r < 4; ++r) {
#pragma unroll
            for (int s = 0; s < 4; ++s) {
                float sc = cna[s] - 2.f * acc[r][s];
                // strict < keeps earliest n (ascending visit order) => jnp.argmin tie-break
                if (sc < minv[r]) { minv[r] = sc; minn[r] = n0 + tj * 4 + s; }
            }
        }
    }

    // ---- Phase 3: cross-thread argmin per l (16 tj candidates) ----
#pragma unroll
    for (int r = 0; r < 4; ++r) {
        red_v[(ti * 4 + r) * 17 + tj] = minv[r];
        red_n[(ti * 4 + r) * 17 + tj] = minn[r];
    }
    __syncthreads();
    if (tid < TL) {
        float bv = red_v[tid * 17];
        int   bn = red_n[tid * 17];
#pragma unroll
        for (int j = 1; j < 16; ++j) {
            float v = red_v[tid * 17 + j];
            int   n = red_n[tid * 17 + j];
            if (v < bv || (v == bv && n < bn)) { bv = v; bn = n; }
        }
        idx_final[tid] = bn;
        out1[((size_t)b * LL + l0 + tid) * KK + k] = (float)bn;
    }
    __syncthreads();

    // ---- Phase 4: cumulative output plane k = prev + cb[idx] ----
    {
        const int ll = tid & 63;
        const int d0 = tid >> 6;
        const int n = idx_final[ll];
        const float* crow = cbk + (size_t)n * DD;
#pragma unroll
        for (int i = 0; i < DD / 4; ++i) {
            int d = d0 + i * 4;
            float p = (k > 0) ? prev[(size_t)d * LL + l0 + ll] : 0.f;
            cur[(size_t)d * LL + l0 + ll] = p + crow[d];
        }
    }
}

extern "C" void kernel_launch(void* const* d_in, const int* in_sizes, int n_in,
                              void* d_out, int out_size, void* d_ws, size_t ws_size,
                              hipStream_t stream) {
    const float* x  = (const float*)d_in[0];   // (B, D, L)
    const float* cb = (const float*)d_in[1];   // (K, N, D)
    float* out0 = (float*)d_out;                         // (B, K, D, L)
    float* out1 = out0 + (size_t)BB * KK * DD * LL;      // (B, L, K)
    float* cnorm = (float*)d_ws;                         // K*N floats (32 KB)

    cnorm_kernel<<<(KK * NN) / 256, 256, 0, stream>>>(cb, cnorm);
    for (int k = 0; k < KK; ++k) {
        rvq_step<<<BB * (LL / TL), 256, 0, stream>>>(
            x, cb + (size_t)k * NN * DD, cnorm + (size_t)k * NN, out0, out1, k);
    }
}

// Round 2
// 2995.061 us; speedup vs baseline: 1.1664x; 1.1664x over previous
//
#include <hip/hip_runtime.h>

// Residual VQ: B=16, D=128, L=4096, K=8 codebooks x N=1024 entries.
// out0 (B,K,D,L) cumulative quantization sums, out1 (B,L,K) argmin indices.
//
// R1 changes vs R0:
//  - cs codebook tile: CSTR 68 -> 64 with XOR chunk swizzle (phys = dq ^ tj).
//    R0's CSTR=68 put the 16 tj-reader rows on 2 bank classes (8-way conflict,
//    SQ_LDS_BANK_CONFLICT ~37% of cycles). Swizzle makes all cv reads 2-way (free).
//  - argmin cross-thread reduction: LDS tables -> packed (score,n) uint64
//    __shfl_xor over the 16-lane tj group. Saves 8.7 KB LDS + 2 barriers.
//  - LDS 60416 -> 50432 B => 3 blocks/CU (__launch_bounds__(256,3)).

#define BB 16
#define DD 128
#define LL 4096
#define KK 8
#define NN 1024

constexpr int TL = 64;            // l-positions per block
constexpr int TN = 64;            // n per chunk
constexpr int NCHUNK = NN / TN;   // 16
constexpr int XSTR = DD + 4;      // 132: l-rows land 2-way in banks (free), keeps 16B align

__global__ void cnorm_kernel(const float* __restrict__ cb, float* __restrict__ cnorm) {
    int row = blockIdx.x * blockDim.x + threadIdx.x;   // 0..K*N-1
    const float4* p = (const float4*)(cb + (size_t)row * DD);
    float s = 0.f;
#pragma unroll
    for (int i = 0; i < DD / 4; ++i) {
        float4 v = p[i];
        s += v.x * v.x + v.y * v.y + v.z * v.z + v.w * v.w;
    }
    cnorm[row] = s;
}

__global__ __launch_bounds__(256, 3) void rvq_step(
    const float* __restrict__ x,
    const float* __restrict__ cbk,     // codebook k base (N*D)
    const float* __restrict__ cnormk,  // N
    float* __restrict__ out0,          // B*K*D*L
    float* __restrict__ out1,          // B*L*K (float-encoded indices)
    int k)
{
    __shared__ float xs[TL * XSTR];    // residual tile [l][d], 33792 B
    __shared__ float cs[TN * 64];      // cb half-chunk [n][16 chunks, XOR-swizzled], 16384 B
    __shared__ int   idx_final[TL];    // 256 B

    const int tid = threadIdx.x;
    const int bidx = blockIdx.x;
    const int b  = bidx / (LL / TL);
    const int l0 = (bidx % (LL / TL)) * TL;

    const float* prev = (k > 0) ? (out0 + ((size_t)b * KK + (k - 1)) * DD * LL) : nullptr;
    float* cur = out0 + ((size_t)b * KK + k) * DD * LL;

    // ---- Phase 1: residual tile -> LDS (coalesced along l) ----
    {
        const int ll = tid & 63;
        const int d0 = tid >> 6;  // 0..3
#pragma unroll
        for (int i = 0; i < DD / 4; ++i) {
            int d = d0 + i * 4;
            size_t gi = ((size_t)b * DD + d) * LL + l0 + ll;
            float v = x[gi];
            if (k > 0) v -= prev[(size_t)d * LL + l0 + ll];
            xs[ll * XSTR + d] = v;
        }
    }
    __syncthreads();

    const int ti = tid >> 4;   // 0..15, owns l = l0 + ti*4 + r
    const int tj = tid & 15;   // 0..15, owns n = n0 + tj*4 + s

    float minv[4];
    int   minn[4];
#pragma unroll
    for (int r = 0; r < 4; ++r) { minv[r] = 3.4e38f; minn[r] = 0; }

    // ---- Phase 2: fused score GEMM + running per-thread argmin ----
    for (int c = 0; c < NCHUNK; ++c) {
        const int n0 = c * TN;
        float acc[4][4];
#pragma unroll
        for (int r = 0; r < 4; ++r)
#pragma unroll
            for (int s = 0; s < 4; ++s) acc[r][s] = 0.f;

#pragma unroll
        for (int h = 0; h < 2; ++h) {
            // stage 64n x 64d half-chunk of cb into LDS, chunk-XOR-swizzled:
            // logical 16B chunk c of row goes to physical chunk c ^ (row>>2).
            {
                const int row = tid >> 2;   // 0..63
                const int q   = tid & 3;    // 0..3
                const float4* src = (const float4*)(cbk + (size_t)(n0 + row) * DD + h * 64);
                float* dstrow = cs + row * 64;
                const int sw = (row >> 2) & 15;
#pragma unroll
                for (int j = 0; j < 4; ++j) {
                    int c4 = q * 4 + j;
                    *(float4*)(dstrow + ((c4 ^ sw) * 4)) = src[c4];
                }
            }
            __syncthreads();
#pragma unroll
            for (int dq = 0; dq < 16; ++dq) {
                float4 xa[4], cv[4];
#pragma unroll
                for (int r = 0; r < 4; ++r)
                    xa[r] = *(const float4*)(xs + (ti * 4 + r) * XSTR + h * 64 + dq * 4);
#pragma unroll
                for (int s = 0; s < 4; ++s)
                    cv[s] = *(const float4*)(cs + (tj * 4 + s) * 64 + ((dq ^ tj) * 4));
#pragma unroll
                for (int r = 0; r < 4; ++r)
#pragma unroll
                    for (int s = 0; s < 4; ++s)
                        acc[r][s] += xa[r].x * cv[s].x + xa[r].y * cv[s].y
                                   + xa[r].z * cv[s].z + xa[r].w * cv[s].w;
            }
            __syncthreads();
        }

        // score = ||c||^2 - 2*dot  (||x||^2 dropped: argmin-invariant)
        float4 cn = *(const float4*)(cnormk + n0 + tj * 4);
        float cna[4] = {cn.x, cn.y, cn.z, cn.w};
#pragma unroll
        for (int r = 0; r < 4; ++r) {
#pragma unroll
            for (int s = 0; s < 4; ++s) {
                float sc = cna[s] - 2.f * acc[r][s];
                // strict < keeps earliest n (ascending visit order) => jnp.argmin tie-break
                if (sc < minv[r]) { minv[r] = sc; minn[r] = n0 + tj * 4 + s; }
            }
        }
    }

    // ---- Phase 3: cross-thread argmin per l via packed-key shuffle over tj group ----
    // key = (monotone(score) << 32) | n : min key == (min score, then min n).
    {
        unsigned long long key[4];
#pragma unroll
        for (int r = 0; r < 4; ++r) {
            unsigned u = __float_as_uint(minv[r]);
            u = (u & 0x80000000u) ? ~u : (u | 0x80000000u);
            key[r] = ((unsigned long long)u << 32) | (unsigned)minn[r];
        }
#pragma unroll
        for (int off = 1; off < 16; off <<= 1) {
#pragma unroll
            for (int r = 0; r < 4; ++r) {
                unsigned long long o = __shfl_xor(key[r], off);
                if (o < key[r]) key[r] = o;
            }
        }
        if (tj == 0) {
#pragma unroll
            for (int r = 0; r < 4; ++r) {
                int n = (int)(key[r] & 0xFFFFFFFFu);
                int l = ti * 4 + r;
                idx_final[l] = n;
                out1[((size_t)b * LL + l0 + l) * KK + k] = (float)n;
            }
        }
    }
    __syncthreads();

    // ---- Phase 4: cumulative output plane k = prev + cb[idx] ----
    {
        const int ll = tid & 63;
        const int d0 = tid >> 6;
        const int n = idx_final[ll];
        const float* crow = cbk + (size_t)n * DD;
#pragma unroll
        for (int i = 0; i < DD / 4; ++i) {
            int d = d0 + i * 4;
            float p = (k > 0) ? prev[(size_t)d * LL + l0 + ll] : 0.f;
            cur[(size_t)d * LL + l0 + ll] = p + crow[d];
        }
    }
}

extern "C" void kernel_launch(void* const* d_in, const int* in_sizes, int n_in,
                              void* d_out, int out_size, void* d_ws, size_t ws_size,
                              hipStream_t stream) {
    const float* x  = (const float*)d_in[0];   // (B, D, L)
    const float* cb = (const float*)d_in[1];   // (K, N, D)
    float* out0 = (float*)d_out;                         // (B, K, D, L)
    float* out1 = out0 + (size_t)BB * KK * DD * LL;      // (B, L, K)
    float* cnorm = (float*)d_ws;                         // K*N floats (32 KB)

    cnorm_kernel<<<(KK * NN) / 256, 256, 0, stream>>>(cb, cnorm);
    for (int k = 0; k < KK; ++k) {
        rvq_step<<<BB * (LL / TL), 256, 0, stream>>>(
            x, cb + (size_t)k * NN * DD, cnorm + (size_t)k * NN, out0, out1, k);
    }
}